// Round 6
// baseline (231.871 us; speedup 1.0000x reference)
//
#include <hip/hip_runtime.h>

#define BB 8
#define CC 64
#define HH 112
#define WW 112
#define HWs (HH * WW)                 // 12544
#define KEYN 9

// ---- conv_key geometry ----
#define CK_PX 128
#define CK_TILES (HWs / CK_PX)        // 98
#define CK_NBLK (BB * CK_TILES)       // 784
#define WTS 68                        // Wt row stride: 16B-aligned rows

// ---- fused sampler geometry ----
#define SM_PX 32
#define SM_TILES (HWs / SM_PX)        // 392
#define SM_NBLK (BB * SM_TILES)       // 3136

// fused-kernel LDS float offsets (phase overlays):
//   phase A (conv+softmax):  Wq[64][20] @2304, Sb[20] @3584, L[32][21] @3604
//   phase B (table+sample):  Tq[32*9*4] uint2 @0, OutT[32][69] @2304
#define OFF_TQ   0                    // 1152 uint2 = 2304 floats
#define OFF_WQ   2304
#define OFF_SB   3584
#define OFF_L    3604
#define OFF_OUTT 2304
#define SM_LDS   4512                 // 18.0 KB -> 8 blocks/CU

// quad-wide sum via DPP (VALU pipe, no LDS): lanes get v + v^1 + v^2 + v^3
__device__ __forceinline__ float qsum(float v) {
    int a = __builtin_amdgcn_mov_dpp(__float_as_int(v), 0xB1, 0xF, 0xF, true);  // [1,0,3,2]
    float s = v + __int_as_float(a);
    int b = __builtin_amdgcn_mov_dpp(__float_as_int(s), 0x4E, 0xF, 0xF, true);  // [2,3,0,1]
    return s + __int_as_float(b);
}

// ---------------------------------------------------------------------------
// conv_key: Kf[b*HW+px][64] = W_refer @ key + b_refer  (pixel-major)
// 256 thr, 128-px tile; thread = (pg=t&15 -> px 8pg..8pg+7, og=t>>4 -> outs
// 4og..4og+3). Input DIRECT global->reg (wave-dedup'd 512B rows, L1-served);
// only weights via LDS: 1 broadcast ds_read_b128 per k per wave.
// ---------------------------------------------------------------------------
__global__ __launch_bounds__(256, 4) void conv_key_kernel(
    const float* __restrict__ key, const float* __restrict__ w_refer,
    const float* __restrict__ b_refer, float* __restrict__ Kf)
{
    __shared__ float Wt[64 * WTS];      // [k][o] 17.4 KB

    const int t = threadIdx.x;
    const int blk = blockIdx.x;
    const int b = blk / CK_TILES;
    const int s0 = (blk - b * CK_TILES) * CK_PX;

    // stage transposed weights [k][o] (one-time scatter)
    #pragma unroll
    for (int m = 0; m < 4; ++m) {
        const int f = t + 256 * m;
        const int o = f >> 4;
        const int q = f & 15;
        const float4 wv = *reinterpret_cast<const float4*>(w_refer + o * CC + 4 * q);
        Wt[(4 * q + 0) * WTS + o] = wv.x;
        Wt[(4 * q + 1) * WTS + o] = wv.y;
        Wt[(4 * q + 2) * WTS + o] = wv.z;
        Wt[(4 * q + 3) * WTS + o] = wv.w;
    }
    __syncthreads();

    const int pg = t & 15;
    const int og = t >> 4;
    const size_t inb = (size_t)b * CC * HWs + s0 + 8 * pg;

    const float4 bias = *reinterpret_cast<const float4*>(b_refer + 4 * og);
    float4 acc[8];                      // [px] x 4 outs
    #pragma unroll
    for (int p = 0; p < 8; ++p) acc[p] = bias;

    #pragma unroll 2
    for (int k = 0; k < 64; ++k) {
        const float4 i0 = *reinterpret_cast<const float4*>(key + inb + (size_t)k * HWs);
        const float4 i1 = *reinterpret_cast<const float4*>(key + inb + (size_t)k * HWs + 4);
        const float4 wv = *reinterpret_cast<const float4*>(&Wt[k * WTS + 4 * og]);
        const float ip[8] = {i0.x, i0.y, i0.z, i0.w, i1.x, i1.y, i1.z, i1.w};
        #pragma unroll
        for (int p = 0; p < 8; ++p) {
            acc[p].x = fmaf(ip[p], wv.x, acc[p].x);
            acc[p].y = fmaf(ip[p], wv.y, acc[p].y);
            acc[p].z = fmaf(ip[p], wv.z, acc[p].z);
            acc[p].w = fmaf(ip[p], wv.w, acc[p].w);
        }
    }

    const size_t ob = ((size_t)b * HWs + s0 + 8 * pg) * CC + 4 * og;
    #pragma unroll
    for (int p = 0; p < 8; ++p)
        *reinterpret_cast<float4*>(Kf + ob + (size_t)p * CC) = acc[p];
}

// ---------------------------------------------------------------------------
// Fused: query conv (direct global reads) -> softmax -> (addr,wk) table ->
// sampling (DPP quad reduction) -> transposed store.
// 256 thr, 32-px tile, batch = blockIdx&7 (batch<->XCD L2 locality).
// LDS 18 KB -> 8 blocks/CU requested.
// ---------------------------------------------------------------------------
__global__ __launch_bounds__(256, 8) void fused_sample_kernel(
    const float* __restrict__ query, const float* __restrict__ w_attn,
    const float* __restrict__ b_attn, const float* __restrict__ w_off,
    const float* __restrict__ b_off, const float* __restrict__ Kf,
    float* __restrict__ out)
{
    __shared__ float S[SM_LDS];
    uint2* Tq   = reinterpret_cast<uint2*>(S + OFF_TQ);   // [32*9*4]
    float* Wq   = S + OFF_WQ;     // [64][20]
    float* Sb   = S + OFF_SB;     // [20]
    float* L    = S + OFF_L;      // [32][21]
    float* OutT = S + OFF_OUTT;   // [32][69] overlays Wq/Sb/L (dead by then)

    const int t = threadIdx.x;
    const int l = t & 63;
    const int w = t >> 6;
    const int blk = blockIdx.x;
    const int b = blk & 7;                       // batch == XCD round-robin
    const int tile = blk >> 3;
    const int s0 = tile * SM_PX;
    const size_t qb = (size_t)b * CC * HWs + s0;
    const char* Kfb = reinterpret_cast<const char*>(Kf) + (size_t)b * HWs * CC * 4;

    // ---- stage transposed query weights [k][20] + biases (only LDS staging)
    for (int f = t; f < 304; f += 256) {
        const int r = f >> 4;
        const int q = f & 15;
        const float* src = (r < KEYN) ? (w_attn + r * CC) : (w_off + (r - KEYN) * CC);
        const float4 wv = *reinterpret_cast<const float4*>(src + 4 * q);
        Wq[(4 * q + 0) * 20 + r] = wv.x;
        Wq[(4 * q + 1) * 20 + r] = wv.y;
        Wq[(4 * q + 2) * 20 + r] = wv.z;
        Wq[(4 * q + 3) * 20 + r] = wv.w;
    }
    if (t < 64) Wq[t * 20 + 19] = 0.f;
    if (t < 20) Sb[t] = (t < KEYN) ? b_attn[t] : (t < 19 ? b_off[t - KEYN] : 0.f);
    __syncthreads();

    // ---- query conv: thread = (px = t&31, og = t>>5 < 5); input from global
    {
        const int px = t & 31;
        const int og = t >> 5;
        if (og < 5) {
            const int o4 = 4 * og;
            float4 acc = *reinterpret_cast<const float4*>(&Sb[o4]);
            #pragma unroll 8
            for (int k = 0; k < 64; ++k) {
                const float a = query[qb + (size_t)k * HWs + px];
                const float4 wv = *reinterpret_cast<const float4*>(&Wq[k * 20 + o4]);
                acc.x = fmaf(a, wv.x, acc.x);
                acc.y = fmaf(a, wv.y, acc.y);
                acc.z = fmaf(a, wv.z, acc.z);
                acc.w = fmaf(a, wv.w, acc.w);
            }
            L[px * 21 + o4 + 0] = acc.x;
            L[px * 21 + o4 + 1] = acc.y;
            L[px * 21 + o4 + 2] = acc.z;
            L[px * 21 + o4 + 3] = acc.w;
        }
    }
    __syncthreads();

    // ---- softmax in place: L[p][0..8] <- normalized attn
    if (t < SM_PX) {
        float lg[KEYN];
        #pragma unroll
        for (int k = 0; k < KEYN; ++k) lg[k] = L[t * 21 + k];
        float m = lg[0];
        #pragma unroll
        for (int k = 1; k < KEYN; ++k) m = fmaxf(m, lg[k]);
        float s = 0.f, e[KEYN];
        #pragma unroll
        for (int k = 0; k < KEYN; ++k) { e[k] = expf(lg[k] - m); s += e[k]; }
        const float sinv = 1.0f / s;
        #pragma unroll
        for (int k = 0; k < KEYN; ++k) L[t * 21 + k] = e[k] * sinv;
    }
    __syncthreads();

    // ---- table: (byte addr, wk = corner-weight * attn) per (px,key,corner)
    for (int f = t; f < SM_PX * KEYN * 4; f += 256) {
        const int p = f / 36;
        const int r = f - p * 36;
        const int k = r >> 2;
        const int g = r & 3;
        const int s = s0 + p;
        const int y = s / WW;
        const int x = s - y * WW;
        const float a  = L[p * 21 + k];
        const float dy = L[p * 21 + KEYN + k];
        const float dx = L[p * 21 + KEYN + k + 1];
        const float py = dy + (float)y;
        const float px = dx + (float)x;
        const float fy = floorf(py), fx = floorf(px);
        const int gdy = g >> 1, gdx = g & 1;
        const int iy = (int)fy + gdy;
        const int ix = (int)fx + gdx;
        const int yc = min(max(iy, 0), HH - 1);
        const int xc = min(max(ix, 0), WW - 1);
        const bool valid = (iy >= 0) & (iy < HH) & (ix >= 0) & (ix < WW);
        const float wy = gdy ? (py - fy) : (1.f - (py - fy));
        const float wx = gdx ? (px - fx) : (1.f - (px - fx));
        float wk = wy * wx * a;
        wk = valid ? wk : 0.f;
        const unsigned addr = (unsigned)((yc * WW + xc) * CC * 4);
        Tq[f] = make_uint2(addr, __float_as_uint(wk));
    }
    __syncthreads();

    // ---- sampling: wave w -> px [8w,8w+8) as 4 pairs; DPP quad reduction
    const int g = l & 3;
    const int cb16 = (l >> 2) * 16;

    #pragma unroll
    for (int j = 0; j < 4; ++j) {
        const int p0 = w * 8 + 2 * j;
        const int p1 = p0 + 1;
        const uint2* Tp0 = Tq + p0 * 36 + g;
        const uint2* Tp1 = Tq + p1 * 36 + g;

        float4 a0 = make_float4(0.f, 0.f, 0.f, 0.f);
        float4 a1 = make_float4(0.f, 0.f, 0.f, 0.f);
        #pragma unroll
        for (int k = 0; k < KEYN; ++k) {
            const uint2 e0 = Tp0[k * 4];
            const uint2 e1 = Tp1[k * 4];
            const float4 v0 = *reinterpret_cast<const float4*>(Kfb + (e0.x + cb16));
            const float4 v1 = *reinterpret_cast<const float4*>(Kfb + (e1.x + cb16));
            const float w0 = __uint_as_float(e0.y);
            const float w1 = __uint_as_float(e1.y);
            a0.x = fmaf(v0.x, w0, a0.x); a0.y = fmaf(v0.y, w0, a0.y);
            a0.z = fmaf(v0.z, w0, a0.z); a0.w = fmaf(v0.w, w0, a0.w);
            a1.x = fmaf(v1.x, w1, a1.x); a1.y = fmaf(v1.y, w1, a1.y);
            a1.z = fmaf(v1.z, w1, a1.z); a1.w = fmaf(v1.w, w1, a1.w);
        }

        a0.x = qsum(a0.x); a0.y = qsum(a0.y); a0.z = qsum(a0.z); a0.w = qsum(a0.w);
        a1.x = qsum(a1.x); a1.y = qsum(a1.y); a1.z = qsum(a1.z); a1.w = qsum(a1.w);

        if (g == 0) {
            float* d0 = OutT + p0 * 69 + (cb16 >> 2);
            float* d1 = OutT + p1 * 69 + (cb16 >> 2);
            d0[0] = a0.x; d0[1] = a0.y; d0[2] = a0.z; d0[3] = a0.w;
            d1[0] = a1.x; d1[1] = a1.y; d1[2] = a1.z; d1[3] = a1.w;
        }
    }
    __syncthreads();

    // ---- transposed store: out[b][c][s0+px]
    const size_t ob = (size_t)b * CC * HWs + s0;
    #pragma unroll
    for (int m = 0; m < 8; ++m) {
        const int f = t + 256 * m;
        const int c = f >> 5;
        const int px = f & 31;
        out[ob + (size_t)c * HWs + px] = OutT[px * 69 + c];
    }
}

extern "C" void kernel_launch(void* const* d_in, const int* in_sizes, int n_in,
                              void* d_out, int out_size, void* d_ws, size_t ws_size,
                              hipStream_t stream)
{
    const float* query   = (const float*)d_in[0];
    const float* key     = (const float*)d_in[1];
    const float* w_refer = (const float*)d_in[2];
    const float* b_refer = (const float*)d_in[3];
    const float* w_attn  = (const float*)d_in[4];
    const float* b_attn  = (const float*)d_in[5];
    const float* w_off   = (const float*)d_in[6];
    const float* b_off   = (const float*)d_in[7];
    float* out = (float*)d_out;

    float* Kf = (float*)d_ws;   // [B*HW][64] pixel-major, 25.7 MB

    hipLaunchKernelGGL(conv_key_kernel, dim3(CK_NBLK), dim3(256), 0, stream,
                       key, w_refer, b_refer, Kf);
    hipLaunchKernelGGL(fused_sample_kernel, dim3(SM_NBLK), dim3(256), 0, stream,
                       query, w_attn, b_attn, w_off, b_off, Kf, out);
}

// Round 7
// 162.087 us; speedup vs baseline: 1.4305x; 1.4305x over previous
//
#include <hip/hip_runtime.h>

#define BB 8
#define CC 64
#define HH 112
#define WW 112
#define HWs (HH * WW)                 // 12544
#define KEYN 9

// ---- conv_key geometry (R4/R5 proven version) ----
#define CK_PX 128
#define CK_TILES (HWs / CK_PX)        // 98
#define CK_NBLK (BB * CK_TILES)       // 784
#define WTS 68                        // Wt row stride: 16B-aligned rows

// ---- fused sampler geometry ----
#define SM_PX 32
#define SM_TILES (HWs / SM_PX)        // 392
#define SM_NBLK (BB * SM_TILES)       // 3136

// fused-kernel LDS float offsets (phase overlays):
//   phase A (conv+softmax): Wq[64][20] @2304, Sb[20] @3584, L[32][21] @3604
//   phase B (table+sample): Tq[32*9*2] uint4 @0 (2304 fl), OutT[32][69] @2304
#define OFF_TQ   0
#define OFF_WQ   2304
#define OFF_SB   3584
#define OFF_L    3604
#define OFF_OUTT 2304
#define SM_LDS   4512                 // 18.0 KB

// xor-16 lane swap within 32-lane halves (BitMode: xor=0x10, and=0x1F)
__device__ __forceinline__ float swzx16(float v) {
    return __uint_as_float(__builtin_amdgcn_ds_swizzle(__float_as_uint(v), 0x401F));
}

// ---------------------------------------------------------------------------
// conv_key: Kf[b*HW+px][64] = W_refer @ key + b_refer  (pixel-major)
// R4/R5 structure (measured ~22 us): LDS-staged Xin[k][px] + Wt[k][o];
// thread = (og=t&7 -> 8 outs, p4=t>>3 -> 4 px); 3 ds_read_b128 -> 32 FMA / k.
// ---------------------------------------------------------------------------
__global__ __launch_bounds__(256, 3) void conv_key_kernel(
    const float* __restrict__ key, const float* __restrict__ w_refer,
    const float* __restrict__ b_refer, float* __restrict__ Kf)
{
    __shared__ float Xin[64 * CK_PX];   // 32 KB
    __shared__ float Wt[64 * WTS];      // 17.4 KB

    const int t = threadIdx.x;
    const int blk = blockIdx.x;
    const int b = blk / CK_TILES;
    const int s0 = (blk - b * CK_TILES) * CK_PX;
    const size_t inb = (size_t)b * CC * HWs + s0;

    #pragma unroll
    for (int m = 0; m < 4; ++m) {
        const int f = t + 256 * m;
        const int o = f >> 4;
        const int q = f & 15;
        const float4 wv = *reinterpret_cast<const float4*>(w_refer + o * CC + 4 * q);
        Wt[(4 * q + 0) * WTS + o] = wv.x;
        Wt[(4 * q + 1) * WTS + o] = wv.y;
        Wt[(4 * q + 2) * WTS + o] = wv.z;
        Wt[(4 * q + 3) * WTS + o] = wv.w;
    }
    #pragma unroll
    for (int m = 0; m < 8; ++m) {
        const int f = t + 256 * m;
        const int k = f >> 5;
        const int p8 = f & 31;
        *reinterpret_cast<float4*>(&Xin[k * CK_PX + 4 * p8]) =
            *reinterpret_cast<const float4*>(key + inb + (size_t)k * HWs + 4 * p8);
    }
    __syncthreads();

    const int og = t & 7;
    const int p4 = t >> 3;
    const float4 bias0 = *reinterpret_cast<const float4*>(b_refer + 8 * og);
    const float4 bias1 = *reinterpret_cast<const float4*>(b_refer + 8 * og + 4);
    float4 acc[4][2];
    #pragma unroll
    for (int pi = 0; pi < 4; ++pi) { acc[pi][0] = bias0; acc[pi][1] = bias1; }

    #pragma unroll 4
    for (int k = 0; k < 64; ++k) {
        const float4 a4 = *reinterpret_cast<const float4*>(&Xin[k * CK_PX + 4 * p4]);
        const float4 w0 = *reinterpret_cast<const float4*>(&Wt[k * WTS + 8 * og]);
        const float4 w1 = *reinterpret_cast<const float4*>(&Wt[k * WTS + 8 * og + 4]);
        const float ap[4] = {a4.x, a4.y, a4.z, a4.w};
        #pragma unroll
        for (int pi = 0; pi < 4; ++pi) {
            acc[pi][0].x = fmaf(ap[pi], w0.x, acc[pi][0].x);
            acc[pi][0].y = fmaf(ap[pi], w0.y, acc[pi][0].y);
            acc[pi][0].z = fmaf(ap[pi], w0.z, acc[pi][0].z);
            acc[pi][0].w = fmaf(ap[pi], w0.w, acc[pi][0].w);
            acc[pi][1].x = fmaf(ap[pi], w1.x, acc[pi][1].x);
            acc[pi][1].y = fmaf(ap[pi], w1.y, acc[pi][1].y);
            acc[pi][1].z = fmaf(ap[pi], w1.z, acc[pi][1].z);
            acc[pi][1].w = fmaf(ap[pi], w1.w, acc[pi][1].w);
        }
    }

    #pragma unroll
    for (int pi = 0; pi < 4; ++pi) {
        const size_t ob = ((size_t)b * HWs + s0 + 4 * p4 + pi) * CC + 8 * og;
        *reinterpret_cast<float4*>(Kf + ob)     = acc[pi][0];
        *reinterpret_cast<float4*>(Kf + ob + 4) = acc[pi][1];
    }
}

// ---------------------------------------------------------------------------
// Fused: query conv -> softmax -> row-granular (addr,w) table -> sampling
// with LANE-SEQUENTIAL gathers -> transposed store.
// Lane = (sub=l>>5 pixel, c2=(l>>4)&1 x-corner, cb=l&15 ch-chunk): each
// 32-lane half reads a 512B contiguous corner-row span per key; y-corners
// serial; x-corner pair summed via one xor16 ds_swizzle.
// ---------------------------------------------------------------------------
__global__ __launch_bounds__(256, 8) void fused_sample_kernel(
    const float* __restrict__ query, const float* __restrict__ w_attn,
    const float* __restrict__ b_attn, const float* __restrict__ w_off,
    const float* __restrict__ b_off, const float* __restrict__ Kf,
    float* __restrict__ out)
{
    __shared__ float S[SM_LDS];
    uint4* Tq   = reinterpret_cast<uint4*>(S + OFF_TQ);   // [32*9*2]
    float* Wq   = S + OFF_WQ;     // [64][20]
    float* Sb   = S + OFF_SB;     // [20]
    float* L    = S + OFF_L;      // [32][21]
    float* OutT = S + OFF_OUTT;   // [32][69] overlays Wq/Sb/L (dead by then)

    const int t = threadIdx.x;
    const int l = t & 63;
    const int w = t >> 6;
    const int blk = blockIdx.x;
    const int b = blk & 7;                       // batch == XCD round-robin
    const int tile = blk >> 3;
    const int s0 = tile * SM_PX;
    const size_t qb = (size_t)b * CC * HWs + s0;
    const char* Kfb = reinterpret_cast<const char*>(Kf) + (size_t)b * HWs * CC * 4;

    // ---- stage transposed query weights [k][20] + biases
    for (int f = t; f < 304; f += 256) {
        const int r = f >> 4;
        const int q = f & 15;
        const float* src = (r < KEYN) ? (w_attn + r * CC) : (w_off + (r - KEYN) * CC);
        const float4 wv = *reinterpret_cast<const float4*>(src + 4 * q);
        Wq[(4 * q + 0) * 20 + r] = wv.x;
        Wq[(4 * q + 1) * 20 + r] = wv.y;
        Wq[(4 * q + 2) * 20 + r] = wv.z;
        Wq[(4 * q + 3) * 20 + r] = wv.w;
    }
    if (t < 64) Wq[t * 20 + 19] = 0.f;
    if (t < 20) Sb[t] = (t < KEYN) ? b_attn[t] : (t < 19 ? b_off[t - KEYN] : 0.f);
    __syncthreads();

    // ---- query conv: thread = (px = t&31, og = t>>5 < 5); input from global
    {
        const int px = t & 31;
        const int og = t >> 5;
        if (og < 5) {
            const int o4 = 4 * og;
            float4 acc = *reinterpret_cast<const float4*>(&Sb[o4]);
            #pragma unroll 8
            for (int k = 0; k < 64; ++k) {
                const float a = query[qb + (size_t)k * HWs + px];
                const float4 wv = *reinterpret_cast<const float4*>(&Wq[k * 20 + o4]);
                acc.x = fmaf(a, wv.x, acc.x);
                acc.y = fmaf(a, wv.y, acc.y);
                acc.z = fmaf(a, wv.z, acc.z);
                acc.w = fmaf(a, wv.w, acc.w);
            }
            L[px * 21 + o4 + 0] = acc.x;
            L[px * 21 + o4 + 1] = acc.y;
            L[px * 21 + o4 + 2] = acc.z;
            L[px * 21 + o4 + 3] = acc.w;
        }
    }
    __syncthreads();

    // ---- softmax in place: L[p][0..8] <- normalized attn
    if (t < SM_PX) {
        float lg[KEYN];
        #pragma unroll
        for (int k = 0; k < KEYN; ++k) lg[k] = L[t * 21 + k];
        float m = lg[0];
        #pragma unroll
        for (int k = 1; k < KEYN; ++k) m = fmaxf(m, lg[k]);
        float s = 0.f, e[KEYN];
        #pragma unroll
        for (int k = 0; k < KEYN; ++k) { e[k] = expf(lg[k] - m); s += e[k]; }
        const float sinv = 1.0f / s;
        #pragma unroll
        for (int k = 0; k < KEYN; ++k) L[t * 21 + k] = e[k] * sinv;
    }
    __syncthreads();

    // ---- row-granular table: entry (px,key,row) = {addr_x0, addr_x1, w0, w1}
    for (int f = t; f < SM_PX * KEYN * 2; f += 256) {
        const int p = f / 18;
        const int r = f - p * 18;
        const int k = r >> 1;
        const int row = r & 1;
        const int s = s0 + p;
        const int y = s / WW;
        const int x = s - y * WW;
        const float a  = L[p * 21 + k];
        const float dy = L[p * 21 + KEYN + k];
        const float dx = L[p * 21 + KEYN + k + 1];
        const float py = dy + (float)y;
        const float px = dx + (float)x;
        const float fy = floorf(py), fx = floorf(px);
        const float wy1 = py - fy, wx1 = px - fx;
        const int iy  = (int)fy + row;
        const int ix0 = (int)fx;
        const int ix1 = ix0 + 1;
        const int yc  = min(max(iy, 0), HH - 1);
        const int xc0 = min(max(ix0, 0), WW - 1);
        const int xc1 = min(max(ix1, 0), WW - 1);
        const float vy  = (iy  >= 0 && iy  < HH) ? 1.f : 0.f;
        const float vx0 = (ix0 >= 0 && ix0 < WW) ? 1.f : 0.f;
        const float vx1 = (ix1 >= 0 && ix1 < WW) ? 1.f : 0.f;
        const float wy = (row ? wy1 : (1.f - wy1)) * a * vy;
        uint4 e;
        e.x = (unsigned)((yc * WW + xc0) * (CC * 4));
        e.y = (unsigned)((yc * WW + xc1) * (CC * 4));
        e.z = __float_as_uint((1.f - wx1) * wy * vx0);
        e.w = __float_as_uint(wx1 * wy * vx1);
        Tq[f] = e;
    }
    __syncthreads();

    // ---- sampling: wave w -> px [8w,8w+8) as 4 rounds of a pixel pair
    const int sub  = l >> 5;          // which pixel of the pair
    const int c2   = (l >> 4) & 1;    // x-corner
    const int cb16 = (l & 15) * 16;   // channel-chunk byte offset

    for (int j = 0; j < 4; ++j) {
        const int p = w * 8 + 2 * j + sub;
        const uint4* Tp = Tq + p * 18;

        float4 acc0 = make_float4(0.f, 0.f, 0.f, 0.f);
        float4 acc1 = make_float4(0.f, 0.f, 0.f, 0.f);
        #pragma unroll
        for (int k = 0; k < KEYN; ++k) {
            const uint4 e0 = Tp[2 * k];          // row y0
            const uint4 e1 = Tp[2 * k + 1];      // row y1
            const unsigned ad0 = (c2 ? e0.y : e0.x) + cb16;
            const unsigned ad1 = (c2 ? e1.y : e1.x) + cb16;
            const float w0 = __uint_as_float(c2 ? e0.w : e0.z);
            const float w1 = __uint_as_float(c2 ? e1.w : e1.z);
            const float4 v0 = *reinterpret_cast<const float4*>(Kfb + ad0);
            const float4 v1 = *reinterpret_cast<const float4*>(Kfb + ad1);
            acc0.x = fmaf(v0.x, w0, acc0.x); acc0.y = fmaf(v0.y, w0, acc0.y);
            acc0.z = fmaf(v0.z, w0, acc0.z); acc0.w = fmaf(v0.w, w0, acc0.w);
            acc1.x = fmaf(v1.x, w1, acc1.x); acc1.y = fmaf(v1.y, w1, acc1.y);
            acc1.z = fmaf(v1.z, w1, acc1.z); acc1.w = fmaf(v1.w, w1, acc1.w);
        }
        float4 acc;
        acc.x = acc0.x + acc1.x; acc.y = acc0.y + acc1.y;
        acc.z = acc0.z + acc1.z; acc.w = acc0.w + acc1.w;

        // sum x-corner pair: lane l <-> l^16 (within 32-lane half)
        acc.x += swzx16(acc.x); acc.y += swzx16(acc.y);
        acc.z += swzx16(acc.z); acc.w += swzx16(acc.w);

        if ((l & 16) == 0) {
            float* d = OutT + p * 69 + (cb16 >> 2);
            d[0] = acc.x; d[1] = acc.y; d[2] = acc.z; d[3] = acc.w;
        }
    }
    __syncthreads();

    // ---- transposed store: out[b][c][s0+px]
    const size_t ob = (size_t)b * CC * HWs + s0;
    #pragma unroll
    for (int m = 0; m < 8; ++m) {
        const int f = t + 256 * m;
        const int c = f >> 5;
        const int px = f & 31;
        out[ob + (size_t)c * HWs + px] = OutT[px * 69 + c];
    }
}

extern "C" void kernel_launch(void* const* d_in, const int* in_sizes, int n_in,
                              void* d_out, int out_size, void* d_ws, size_t ws_size,
                              hipStream_t stream)
{
    const float* query   = (const float*)d_in[0];
    const float* key     = (const float*)d_in[1];
    const float* w_refer = (const float*)d_in[2];
    const float* b_refer = (const float*)d_in[3];
    const float* w_attn  = (const float*)d_in[4];
    const float* b_attn  = (const float*)d_in[5];
    const float* w_off   = (const float*)d_in[6];
    const float* b_off   = (const float*)d_in[7];
    float* out = (float*)d_out;

    float* Kf = (float*)d_ws;   // [B*HW][64] pixel-major, 25.7 MB

    hipLaunchKernelGGL(conv_key_kernel, dim3(CK_NBLK), dim3(256), 0, stream,
                       key, w_refer, b_refer, Kf);
    hipLaunchKernelGGL(fused_sample_kernel, dim3(SM_NBLK), dim3(256), 0, stream,
                       query, w_attn, b_attn, w_off, b_off, Kf, out);
}

// Round 8
// 158.217 us; speedup vs baseline: 1.4655x; 1.0245x over previous
//
#include <hip/hip_runtime.h>

#define BB 8
#define CC 64
#define HH 112
#define WW 112
#define HWs (HH * WW)                 // 12544
#define KEYN 9

// ---- conv_key geometry (R4/R5/R7 proven version) ----
#define CK_PX 128
#define CK_TILES (HWs / CK_PX)        // 98
#define CK_NBLK (BB * CK_TILES)       // 784
#define WTS 68                        // Wt row stride: 16B-aligned rows

// ---- fused sampler geometry ----
#define SM_PX 32
#define SM_TILES (HWs / SM_PX)        // 392
#define SM_NBLK (BB * SM_TILES)       // 3136

// fused-kernel LDS float offsets (phase overlays):
//   phase A (conv+softmax): Wq[64][20] @0, Sb[20] @1280, L[32][21] @1300
//   phase B (sampling):     P[32][9] float4 @0 (overlays dead Wq),
//                           OutT[32][68] @1972
#define OFF_WQ   0
#define OFF_SB   1280
#define OFF_L    1300
#define OFF_P    0
#define OFF_OUTT 1972
#define SM_LDS   4148                 // 16.6 KB

// xor-16 lane swap within 32-lane halves (BitMode: xor=0x10, and=0x1F)
__device__ __forceinline__ float swzx16(float v) {
    return __uint_as_float(__builtin_amdgcn_ds_swizzle(__float_as_uint(v), 0x401F));
}

// ---------------------------------------------------------------------------
// conv_key: Kf[b*HW+px][64] = W_refer @ key + b_refer  (pixel-major)
// LDS-staged Xin[k][px] + Wt[k][o]; thread = (og=t&7 -> 8 outs,
// p4=t>>3 -> 4 px); 3 ds_read_b128 -> 32 FMA per k. (unchanged, ~25 us)
// ---------------------------------------------------------------------------
__global__ __launch_bounds__(256, 3) void conv_key_kernel(
    const float* __restrict__ key, const float* __restrict__ w_refer,
    const float* __restrict__ b_refer, float* __restrict__ Kf)
{
    __shared__ float Xin[64 * CK_PX];   // 32 KB
    __shared__ float Wt[64 * WTS];      // 17.4 KB

    const int t = threadIdx.x;
    const int blk = blockIdx.x;
    const int b = blk / CK_TILES;
    const int s0 = (blk - b * CK_TILES) * CK_PX;
    const size_t inb = (size_t)b * CC * HWs + s0;

    #pragma unroll
    for (int m = 0; m < 4; ++m) {
        const int f = t + 256 * m;
        const int o = f >> 4;
        const int q = f & 15;
        const float4 wv = *reinterpret_cast<const float4*>(w_refer + o * CC + 4 * q);
        Wt[(4 * q + 0) * WTS + o] = wv.x;
        Wt[(4 * q + 1) * WTS + o] = wv.y;
        Wt[(4 * q + 2) * WTS + o] = wv.z;
        Wt[(4 * q + 3) * WTS + o] = wv.w;
    }
    #pragma unroll
    for (int m = 0; m < 8; ++m) {
        const int f = t + 256 * m;
        const int k = f >> 5;
        const int p8 = f & 31;
        *reinterpret_cast<float4*>(&Xin[k * CK_PX + 4 * p8]) =
            *reinterpret_cast<const float4*>(key + inb + (size_t)k * HWs + 4 * p8);
    }
    __syncthreads();

    const int og = t & 7;
    const int p4 = t >> 3;
    const float4 bias0 = *reinterpret_cast<const float4*>(b_refer + 8 * og);
    const float4 bias1 = *reinterpret_cast<const float4*>(b_refer + 8 * og + 4);
    float4 acc[4][2];
    #pragma unroll
    for (int pi = 0; pi < 4; ++pi) { acc[pi][0] = bias0; acc[pi][1] = bias1; }

    #pragma unroll 4
    for (int k = 0; k < 64; ++k) {
        const float4 a4 = *reinterpret_cast<const float4*>(&Xin[k * CK_PX + 4 * p4]);
        const float4 w0 = *reinterpret_cast<const float4*>(&Wt[k * WTS + 8 * og]);
        const float4 w1 = *reinterpret_cast<const float4*>(&Wt[k * WTS + 8 * og + 4]);
        const float ap[4] = {a4.x, a4.y, a4.z, a4.w};
        #pragma unroll
        for (int pi = 0; pi < 4; ++pi) {
            acc[pi][0].x = fmaf(ap[pi], w0.x, acc[pi][0].x);
            acc[pi][0].y = fmaf(ap[pi], w0.y, acc[pi][0].y);
            acc[pi][0].z = fmaf(ap[pi], w0.z, acc[pi][0].z);
            acc[pi][0].w = fmaf(ap[pi], w0.w, acc[pi][0].w);
            acc[pi][1].x = fmaf(ap[pi], w1.x, acc[pi][1].x);
            acc[pi][1].y = fmaf(ap[pi], w1.y, acc[pi][1].y);
            acc[pi][1].z = fmaf(ap[pi], w1.z, acc[pi][1].z);
            acc[pi][1].w = fmaf(ap[pi], w1.w, acc[pi][1].w);
        }
    }

    #pragma unroll
    for (int pi = 0; pi < 4; ++pi) {
        const size_t ob = ((size_t)b * HWs + s0 + 4 * p4 + pi) * CC + 8 * og;
        *reinterpret_cast<float4*>(Kf + ob)     = acc[pi][0];
        *reinterpret_cast<float4*>(Kf + ob + 4) = acc[pi][1];
    }
}

// ---------------------------------------------------------------------------
// Fused: query conv -> softmax -> packed P{attn,dy,dx} -> sampling with
// INLINE per-lane addr/weight compute (VALU) + lane-sequential gathers.
// Lane = (sub=l>>5 pixel, c2=(l>>4)&1 x-corner, cb=l&15 ch-chunk); per
// (px,key): 1 broadcast ds_read_b128 of P + 2 row gathers (512B spans).
// ---------------------------------------------------------------------------
__global__ __launch_bounds__(256, 8) void fused_sample_kernel(
    const float* __restrict__ query, const float* __restrict__ w_attn,
    const float* __restrict__ b_attn, const float* __restrict__ w_off,
    const float* __restrict__ b_off, const float* __restrict__ Kf,
    float* __restrict__ out)
{
    __shared__ float S[SM_LDS];
    float*  Wq   = S + OFF_WQ;     // [64][20]
    float*  Sb   = S + OFF_SB;     // [20]
    float*  L    = S + OFF_L;      // [32][21]
    float4* Pf   = reinterpret_cast<float4*>(S + OFF_P);   // [32*9] {a,dy,dx,-}
    float*  OutT = S + OFF_OUTT;   // [32][68]

    const int t = threadIdx.x;
    const int l = t & 63;
    const int w = t >> 6;
    const int blk = blockIdx.x;
    const int b = blk & 7;                       // batch == XCD round-robin
    const int tile = blk >> 3;
    const int s0 = tile * SM_PX;
    const size_t qb = (size_t)b * CC * HWs + s0;
    const char* Kfb = reinterpret_cast<const char*>(Kf) + (size_t)b * HWs * CC * 4;

    // ---- stage transposed query weights [k][20] + biases
    for (int f = t; f < 304; f += 256) {
        const int r = f >> 4;
        const int q = f & 15;
        const float* src = (r < KEYN) ? (w_attn + r * CC) : (w_off + (r - KEYN) * CC);
        const float4 wv = *reinterpret_cast<const float4*>(src + 4 * q);
        Wq[(4 * q + 0) * 20 + r] = wv.x;
        Wq[(4 * q + 1) * 20 + r] = wv.y;
        Wq[(4 * q + 2) * 20 + r] = wv.z;
        Wq[(4 * q + 3) * 20 + r] = wv.w;
    }
    if (t < 64) Wq[t * 20 + 19] = 0.f;
    if (t < 20) Sb[t] = (t < KEYN) ? b_attn[t] : (t < 19 ? b_off[t - KEYN] : 0.f);
    __syncthreads();

    // ---- query conv: thread = (px = t&31, og = t>>5 < 5); input from global
    {
        const int px = t & 31;
        const int og = t >> 5;
        if (og < 5) {
            const int o4 = 4 * og;
            float4 acc = *reinterpret_cast<const float4*>(&Sb[o4]);
            #pragma unroll 8
            for (int k = 0; k < 64; ++k) {
                const float a = query[qb + (size_t)k * HWs + px];
                const float4 wv = *reinterpret_cast<const float4*>(&Wq[k * 20 + o4]);
                acc.x = fmaf(a, wv.x, acc.x);
                acc.y = fmaf(a, wv.y, acc.y);
                acc.z = fmaf(a, wv.z, acc.z);
                acc.w = fmaf(a, wv.w, acc.w);
            }
            L[px * 21 + o4 + 0] = acc.x;
            L[px * 21 + o4 + 1] = acc.y;
            L[px * 21 + o4 + 2] = acc.z;
            L[px * 21 + o4 + 3] = acc.w;
        }
    }
    __syncthreads();

    // ---- softmax + pack P[p][k] = {attn, dy, dx, 0} (overlays dead Wq)
    if (t < SM_PX) {
        float lg[KEYN], of[10];
        #pragma unroll
        for (int k = 0; k < KEYN; ++k) lg[k] = L[t * 21 + k];
        #pragma unroll
        for (int j = 0; j < 10; ++j) of[j] = L[t * 21 + KEYN + j];
        float m = lg[0];
        #pragma unroll
        for (int k = 1; k < KEYN; ++k) m = fmaxf(m, lg[k]);
        float s = 0.f, e[KEYN];
        #pragma unroll
        for (int k = 0; k < KEYN; ++k) { e[k] = expf(lg[k] - m); s += e[k]; }
        const float sinv = 1.0f / s;
        #pragma unroll
        for (int k = 0; k < KEYN; ++k)
            Pf[t * KEYN + k] = make_float4(e[k] * sinv, of[k], of[k + 1], 0.f);
    }
    __syncthreads();

    // ---- sampling: wave w -> px [8w,8w+8) as 4 rounds of a pixel pair
    const int sub  = l >> 5;          // which pixel of the pair
    const int c2   = (l >> 4) & 1;    // x-corner
    const int cb16 = (l & 15) * 16;   // channel-chunk byte offset
    const float fc2 = (float)c2;

    for (int j = 0; j < 4; ++j) {
        const int p = w * 8 + 2 * j + sub;
        const int s = s0 + p;
        const int y = s / WW;
        const int x = s - y * WW;
        const float4* Pp = Pf + p * KEYN;

        float4 acc0 = make_float4(0.f, 0.f, 0.f, 0.f);
        float4 acc1 = make_float4(0.f, 0.f, 0.f, 0.f);
        #pragma unroll
        for (int k = 0; k < KEYN; ++k) {
            const float4 pk = Pp[k];                 // broadcast (2 addrs/wave)
            const float py  = pk.y + (float)y;
            const float pxx = pk.z + (float)x;
            const float fy = floorf(py), fx = floorf(pxx);
            const float wy1 = py - fy, wx1 = pxx - fx;
            const int ix = (int)fx + c2;
            const int xc = min(max(ix, 0), WW - 1);
            const float vx = (ix >= 0 && ix < WW) ? 1.f : 0.f;
            const float wx = (fc2 * wx1 + (1.f - fc2) * (1.f - wx1)) * vx * pk.x;
            const int iy0 = (int)fy, iy1 = iy0 + 1;
            const int yc0 = min(max(iy0, 0), HH - 1);
            const int yc1 = min(max(iy1, 0), HH - 1);
            const float w0 = ((iy0 >= 0 && iy0 < HH) ? 1.f : 0.f) * (1.f - wy1) * wx;
            const float w1 = ((iy1 >= 0 && iy1 < HH) ? 1.f : 0.f) * wy1 * wx;
            const unsigned a0 = (unsigned)((yc0 * WW + xc) * (CC * 4)) + cb16;
            const unsigned a1 = (unsigned)((yc1 * WW + xc) * (CC * 4)) + cb16;
            const float4 v0 = *reinterpret_cast<const float4*>(Kfb + a0);
            const float4 v1 = *reinterpret_cast<const float4*>(Kfb + a1);
            acc0.x = fmaf(v0.x, w0, acc0.x); acc0.y = fmaf(v0.y, w0, acc0.y);
            acc0.z = fmaf(v0.z, w0, acc0.z); acc0.w = fmaf(v0.w, w0, acc0.w);
            acc1.x = fmaf(v1.x, w1, acc1.x); acc1.y = fmaf(v1.y, w1, acc1.y);
            acc1.z = fmaf(v1.z, w1, acc1.z); acc1.w = fmaf(v1.w, w1, acc1.w);
        }
        float4 acc;
        acc.x = acc0.x + acc1.x; acc.y = acc0.y + acc1.y;
        acc.z = acc0.z + acc1.z; acc.w = acc0.w + acc1.w;

        // fold x-corner pair: lane l <-> l^16 (within 32-lane half)
        acc.x += swzx16(acc.x); acc.y += swzx16(acc.y);
        acc.z += swzx16(acc.z); acc.w += swzx16(acc.w);

        if ((l & 16) == 0) {
            float* d = OutT + p * 68 + (cb16 >> 2);
            *reinterpret_cast<float4*>(d) = acc;     // 16B-aligned (stride 272B)
        }
    }
    __syncthreads();

    // ---- transposed store: out[b][c][s0+px]
    const size_t ob = (size_t)b * CC * HWs + s0;
    #pragma unroll
    for (int m = 0; m < 8; ++m) {
        const int f = t + 256 * m;
        const int c = f >> 5;
        const int px = f & 31;
        out[ob + (size_t)c * HWs + px] = OutT[px * 68 + c];
    }
}

extern "C" void kernel_launch(void* const* d_in, const int* in_sizes, int n_in,
                              void* d_out, int out_size, void* d_ws, size_t ws_size,
                              hipStream_t stream)
{
    const float* query   = (const float*)d_in[0];
    const float* key     = (const float*)d_in[1];
    const float* w_refer = (const float*)d_in[2];
    const float* b_refer = (const float*)d_in[3];
    const float* w_attn  = (const float*)d_in[4];
    const float* b_attn  = (const float*)d_in[5];
    const float* w_off   = (const float*)d_in[6];
    const float* b_off   = (const float*)d_in[7];
    float* out = (float*)d_out;

    float* Kf = (float*)d_ws;   // [B*HW][64] pixel-major, 25.7 MB

    hipLaunchKernelGGL(conv_key_kernel, dim3(CK_NBLK), dim3(256), 0, stream,
                       key, w_refer, b_refer, Kf);
    hipLaunchKernelGGL(fused_sample_kernel, dim3(SM_NBLK), dim3(256), 0, stream,
                       query, w_attn, b_attn, w_off, b_off, Kf, out);
}